// Round 1
// baseline (438.944 us; speedup 1.0000x reference)
//
#include <hip/hip_runtime.h>

// MHA forward, bf16-MFMA pipeline.
// ws layout (88MB total): xb(16M) | Wqkv_t(6M) | Wo_t(2M) | Q(16M) | K(16M) | Vt(16M) | AO(16M)

typedef short short8 __attribute__((ext_vector_type(8)));
typedef float f32x4 __attribute__((ext_vector_type(4)));

#define DMODEL 1024
#define NH 16
#define DK 64
#define SEQ 2048
#define NB 4
#define MTOT (NB*SEQ)   // 8192

__device__ __forceinline__ unsigned short f2bf(float f) {
    union { float f; unsigned u; } v; v.f = f;
    unsigned r = (v.u + 0x7FFFu + ((v.u >> 16) & 1u)) >> 16;  // RNE
    return (unsigned short)r;
}

// ---------- fp32 -> bf16 convert (vectorized) ----------
__global__ __launch_bounds__(256) void cvt_kernel(const float* __restrict__ in,
                                                  short* __restrict__ out, int n4) {
    int i = blockIdx.x * 256 + threadIdx.x;
    if (i >= n4) return;
    float4 v = ((const float4*)in)[i];
    short4 o;
    o.x = (short)f2bf(v.x); o.y = (short)f2bf(v.y);
    o.z = (short)f2bf(v.z); o.w = (short)f2bf(v.w);
    ((short4*)out)[i] = o;
}

// ---------- W[K][N] fp32 -> Wt[N][K] bf16 ----------
__global__ __launch_bounds__(256) void transpose_kernel(const float* __restrict__ W,
                                                        short* __restrict__ Wt) {
    __shared__ float t[32][33];
    int r0 = blockIdx.y * 32, c0 = blockIdx.x * 32;
    int tr = threadIdx.x >> 3;
    int tc = (threadIdx.x & 7) * 4;
    float4 v = *(const float4*)&W[(r0 + tr) * DMODEL + c0 + tc];
    t[tr][tc + 0] = v.x; t[tr][tc + 1] = v.y; t[tr][tc + 2] = v.z; t[tr][tc + 3] = v.w;
    __syncthreads();
    short4 o;
    o.x = (short)f2bf(t[tc + 0][tr]);
    o.y = (short)f2bf(t[tc + 1][tr]);
    o.z = (short)f2bf(t[tc + 2][tr]);
    o.w = (short)f2bf(t[tc + 3][tr]);
    *(short4*)&Wt[(c0 + tr) * DMODEL + r0 + tc] = o;
}

// ---------- 128x128 tile bf16 GEMM: C[M][N] = A[M][K] * Bt[N][K]^T (+bias) ----------
// MODE 0: QKV projection -> route into Qb/Kb (b,h,s,d) and Vtb (b,h,d,s), bf16.
// MODE 1: out projection -> fp32 d_out with bias b0.
template<int MODE>
__global__ __launch_bounds__(256) void gemm_kernel(
    const short* __restrict__ A, const short* __restrict__ Bt,
    const float* __restrict__ b0, const float* __restrict__ b1, const float* __restrict__ b2,
    short* __restrict__ Qb, short* __restrict__ Kb, short* __restrict__ Vtb,
    float* __restrict__ Cout)
{
    __shared__ short As[128 * 72];   // 128 rows x (64+8 pad)
    __shared__ short Bs[128 * 72];
    const int K = DMODEL;
    int m0 = blockIdx.y * 128, n0 = blockIdx.x * 128;
    int tid = threadIdx.x, lane = tid & 63, wid = tid >> 6;
    int wm = (wid >> 1) * 64, wn = (wid & 1) * 64;

    f32x4 acc[4][4];
    #pragma unroll
    for (int i = 0; i < 4; i++)
        #pragma unroll
        for (int j = 0; j < 4; j++) acc[i][j] = (f32x4){0.f, 0.f, 0.f, 0.f};

    for (int kt = 0; kt < K; kt += 64) {
        #pragma unroll
        for (int i = 0; i < 4; ++i) {
            int ch = tid + 256 * i;
            int row = ch >> 3, c8 = (ch & 7) * 8;
            *(short8*)&As[row * 72 + c8] = *(const short8*)&A[(m0 + row) * K + kt + c8];
            *(short8*)&Bs[row * 72 + c8] = *(const short8*)&Bt[(n0 + row) * K + kt + c8];
        }
        __syncthreads();
        #pragma unroll
        for (int kk = 0; kk < 2; ++kk) {
            int ko = kk * 32 + (lane >> 4) * 8;
            short8 af[4], bfv[4];
            #pragma unroll
            for (int i = 0; i < 4; i++)
                af[i] = *(const short8*)&As[(wm + i * 16 + (lane & 15)) * 72 + ko];
            #pragma unroll
            for (int j = 0; j < 4; j++)
                bfv[j] = *(const short8*)&Bs[(wn + j * 16 + (lane & 15)) * 72 + ko];
            #pragma unroll
            for (int i = 0; i < 4; i++)
                #pragma unroll
                for (int j = 0; j < 4; j++)
                    acc[i][j] = __builtin_amdgcn_mfma_f32_16x16x32_bf16(af[i], bfv[j], acc[i][j], 0, 0, 0);
        }
        __syncthreads();
    }

    // epilogue: C/D layout col=lane&15, row=(lane>>4)*4+reg
    #pragma unroll
    for (int i = 0; i < 4; i++) {
        #pragma unroll
        for (int j = 0; j < 4; j++) {
            int col = n0 + wn + j * 16 + (lane & 15);
            #pragma unroll
            for (int r = 0; r < 4; r++) {
                int row = m0 + wm + i * 16 + (lane >> 4) * 4 + r;
                float v = acc[i][j][r];
                if (MODE == 0) {
                    int seg = col >> 10, c = col & 1023;
                    const float* bp = (seg == 0) ? b0 : (seg == 1 ? b1 : b2);
                    v += bp[c];
                    unsigned short bv = f2bf(v);
                    int hh = c >> 6, d = c & 63, bb = row >> 11, s = row & 2047;
                    if (seg == 0)      Qb [(((bb * NH + hh) * SEQ) + s) * DK + d] = (short)bv;
                    else if (seg == 1) Kb [(((bb * NH + hh) * SEQ) + s) * DK + d] = (short)bv;
                    else               Vtb[(((bb * NH + hh) * DK) + d) * SEQ + s] = (short)bv;
                } else {
                    Cout[row * DMODEL + col] = v + b0[col];
                }
            }
        }
    }
}

// ---------- flash attention: 128 q-rows/block, KV tiles of 64 ----------
__global__ __launch_bounds__(256) void attn_kernel(
    const short* __restrict__ Qb, const short* __restrict__ Kb,
    const short* __restrict__ Vtb, short* __restrict__ AOb)
{
    __shared__ short Ks[64 * 72];        // [kv][d+pad]
    __shared__ short Vs[64 * 72];        // [d][kv+pad]
    __shared__ short Ps[4 * 32 * 72];    // per-wave P tile [q32][kv64+pad]
    int b = blockIdx.z, h = blockIdx.y, q0 = blockIdx.x * 128;
    int tid = threadIdx.x, lane = tid & 63, wid = tid >> 6;
    int bh = b * NH + h;
    const short* Qp = Qb + bh * SEQ * DK;
    const short* Kp = Kb + bh * SEQ * DK;
    const short* Vp = Vtb + bh * DK * SEQ;
    short* Pw = Ps + wid * 32 * 72;

    // Q fragments in registers: 32 rows x 64 d per wave
    short8 qf[2][2];
    #pragma unroll
    for (int i = 0; i < 2; i++)
        #pragma unroll
        for (int kk = 0; kk < 2; kk++)
            qf[i][kk] = *(const short8*)&Qp[(q0 + wid * 32 + i * 16 + (lane & 15)) * DK
                                            + kk * 32 + (lane >> 4) * 8];

    f32x4 o[2][4];
    float mrun[2][4], lrun[2][4];
    #pragma unroll
    for (int i = 0; i < 2; i++)
        #pragma unroll
        for (int r = 0; r < 4; r++) { mrun[i][r] = -1e30f; lrun[i][r] = 0.f; }
    #pragma unroll
    for (int i = 0; i < 2; i++)
        #pragma unroll
        for (int n = 0; n < 4; n++) o[i][n] = (f32x4){0.f, 0.f, 0.f, 0.f};

    for (int kv0 = 0; kv0 < SEQ; kv0 += 64) {
        // stage K tile [64 kv][64 d] and Vt tile [64 d][64 kv]
        #pragma unroll
        for (int i = 0; i < 2; ++i) {
            int ch = tid + 256 * i;
            int row = ch >> 3, c8 = (ch & 7) * 8;
            *(short8*)&Ks[row * 72 + c8] = *(const short8*)&Kp[(kv0 + row) * DK + c8];
            *(short8*)&Vs[row * 72 + c8] = *(const short8*)&Vp[row * SEQ + kv0 + c8];
        }
        __syncthreads();

        // S = Q K^T  (A=Q rows, B=K rows; both fragments read rows k-contiguous)
        f32x4 sc[2][4];
        #pragma unroll
        for (int i = 0; i < 2; i++)
            #pragma unroll
            for (int j = 0; j < 4; j++) sc[i][j] = (f32x4){0.f, 0.f, 0.f, 0.f};
        #pragma unroll
        for (int j = 0; j < 4; j++) {
            #pragma unroll
            for (int kk = 0; kk < 2; kk++) {
                short8 kf = *(const short8*)&Ks[(j * 16 + (lane & 15)) * 72
                                                + kk * 32 + (lane >> 4) * 8];
                sc[0][j] = __builtin_amdgcn_mfma_f32_16x16x32_bf16(qf[0][kk], kf, sc[0][j], 0, 0, 0);
                sc[1][j] = __builtin_amdgcn_mfma_f32_16x16x32_bf16(qf[1][kk], kf, sc[1][j], 0, 0, 0);
            }
        }

        // online softmax, wave-parallel (rows live in 16-lane groups)
        #pragma unroll
        for (int i = 0; i < 2; i++) {
            #pragma unroll
            for (int r = 0; r < 4; r++) {
                float mx = -1e30f;
                #pragma unroll
                for (int j = 0; j < 4; j++) {
                    float s = sc[i][j][r] * 0.125f;  // 1/sqrt(64)
                    sc[i][j][r] = s;
                    mx = fmaxf(mx, s);
                }
                #pragma unroll
                for (int off = 1; off < 16; off <<= 1) mx = fmaxf(mx, __shfl_xor(mx, off, 64));
                float mn = fmaxf(mrun[i][r], mx);
                float alpha = __expf(mrun[i][r] - mn);
                mrun[i][r] = mn;
                float ps = 0.f;
                #pragma unroll
                for (int j = 0; j < 4; j++) {
                    float p = __expf(sc[i][j][r] - mn);
                    sc[i][j][r] = p;
                    ps += p;
                }
                #pragma unroll
                for (int off = 1; off < 16; off <<= 1) ps += __shfl_xor(ps, off, 64);
                lrun[i][r] = lrun[i][r] * alpha + ps;
                #pragma unroll
                for (int n = 0; n < 4; n++) o[i][n][r] *= alpha;
            }
        }

        // P -> LDS (re-layout C-frag -> A-frag), bf16
        #pragma unroll
        for (int i = 0; i < 2; i++)
            #pragma unroll
            for (int j = 0; j < 4; j++)
                #pragma unroll
                for (int r = 0; r < 4; r++)
                    Pw[(i * 16 + (lane >> 4) * 4 + r) * 72 + j * 16 + (lane & 15)] =
                        (short)f2bf(sc[i][j][r]);

        __syncthreads();

        // O += P V   (A=P rows, B=Vt rows (=V cols), k-contiguous)
        #pragma unroll
        for (int kk = 0; kk < 2; kk++) {
            int ko = kk * 32 + (lane >> 4) * 8;
            short8 pa[2], vb[4];
            #pragma unroll
            for (int i = 0; i < 2; i++)
                pa[i] = *(const short8*)&Pw[(i * 16 + (lane & 15)) * 72 + ko];
            #pragma unroll
            for (int n = 0; n < 4; n++)
                vb[n] = *(const short8*)&Vs[(n * 16 + (lane & 15)) * 72 + ko];
            #pragma unroll
            for (int i = 0; i < 2; i++)
                #pragma unroll
                for (int n = 0; n < 4; n++)
                    o[i][n] = __builtin_amdgcn_mfma_f32_16x16x32_bf16(pa[i], vb[n], o[i][n], 0, 0, 0);
        }
        __syncthreads();
    }

    // normalize + store attention output as [b][s][h*64+d] bf16 (feeds out-proj GEMM)
    #pragma unroll
    for (int i = 0; i < 2; i++) {
        #pragma unroll
        for (int r = 0; r < 4; r++) {
            float inv = 1.0f / lrun[i][r];
            int s = q0 + wid * 32 + i * 16 + (lane >> 4) * 4 + r;
            #pragma unroll
            for (int n = 0; n < 4; n++) {
                int d = n * 16 + (lane & 15);
                AOb[(b * SEQ + s) * DMODEL + h * DK + d] = (short)f2bf(o[i][n][r] * inv);
            }
        }
    }
}

extern "C" void kernel_launch(void* const* d_in, const int* in_sizes, int n_in,
                              void* d_out, int out_size, void* d_ws, size_t ws_size,
                              hipStream_t stream)
{
    const float* x  = (const float*)d_in[0];
    const float* Wq = (const float*)d_in[1];
    const float* bq = (const float*)d_in[2];
    const float* Wk = (const float*)d_in[3];
    const float* bk = (const float*)d_in[4];
    const float* Wv = (const float*)d_in[5];
    const float* bv = (const float*)d_in[6];
    const float* Wo = (const float*)d_in[7];
    const float* bo = (const float*)d_in[8];
    float* out = (float*)d_out;

    char* w = (char*)d_ws;
    short* xb    = (short*)w; w += (size_t)MTOT * DMODEL * 2;
    short* Wqkvt = (short*)w; w += (size_t)3 * DMODEL * DMODEL * 2;
    short* Wot   = (short*)w; w += (size_t)DMODEL * DMODEL * 2;
    short* Qb    = (short*)w; w += (size_t)MTOT * DMODEL * 2;
    short* Kb    = (short*)w; w += (size_t)MTOT * DMODEL * 2;
    short* Vtb   = (short*)w; w += (size_t)MTOT * DMODEL * 2;
    short* AOb   = (short*)w; w += (size_t)MTOT * DMODEL * 2;

    cvt_kernel<<<(MTOT * DMODEL / 4 + 255) / 256, 256, 0, stream>>>(x, xb, MTOT * DMODEL / 4);

    dim3 tg(32, 32);
    transpose_kernel<<<tg, 256, 0, stream>>>(Wq, Wqkvt);
    transpose_kernel<<<tg, 256, 0, stream>>>(Wk, Wqkvt + DMODEL * DMODEL);
    transpose_kernel<<<tg, 256, 0, stream>>>(Wv, Wqkvt + 2 * DMODEL * DMODEL);
    transpose_kernel<<<tg, 256, 0, stream>>>(Wo, Wot);

    gemm_kernel<0><<<dim3(3 * DMODEL / 128, MTOT / 128), 256, 0, stream>>>(
        xb, Wqkvt, bq, bk, bv, Qb, Kb, Vtb, nullptr);

    attn_kernel<<<dim3(SEQ / 128, NH, NB), 256, 0, stream>>>(Qb, Kb, Vtb, AOb);

    gemm_kernel<1><<<dim3(DMODEL / 128, MTOT / 128), 256, 0, stream>>>(
        AOb, Wot, bo, nullptr, nullptr, nullptr, nullptr, nullptr, out);
}

// Round 2
// 259.335 us; speedup vs baseline: 1.6926x; 1.6926x over previous
//
#include <hip/hip_runtime.h>

// MHA forward, bf16-MFMA pipeline.
// ws layout (88MB total): xb(16M) | Wqkv_t(6M) | Wo_t(2M) | Q(16M) | K(16M) | Vt(16M) | AO(16M)

typedef short short8 __attribute__((ext_vector_type(8)));
typedef float f32x4 __attribute__((ext_vector_type(4)));
typedef float f32x16 __attribute__((ext_vector_type(16)));

#define DMODEL 1024
#define NH 16
#define DK 64
#define SEQ 2048
#define NB 4
#define MTOT (NB*SEQ)   // 8192

__device__ __forceinline__ unsigned short f2bf(float f) {
    union { float f; unsigned u; } v; v.f = f;
    unsigned r = (v.u + 0x7FFFu + ((v.u >> 16) & 1u)) >> 16;  // RNE
    return (unsigned short)r;
}

// packed f32x2 -> bf16x2 (lo = a, hi = b)
__device__ __forceinline__ unsigned pk2(float a, float b) {
    unsigned r;
    asm("v_cvt_pk_bf16_f32 %0, %1, %2" : "=v"(r) : "v"(a), "v"(b));
    return r;
}

union Frag { short8 s8; unsigned u[4]; };

// ---------- fp32 -> bf16 convert (vectorized) ----------
__global__ __launch_bounds__(256) void cvt_kernel(const float* __restrict__ in,
                                                  short* __restrict__ out, int n4) {
    int i = blockIdx.x * 256 + threadIdx.x;
    if (i >= n4) return;
    float4 v = ((const float4*)in)[i];
    short4 o;
    o.x = (short)f2bf(v.x); o.y = (short)f2bf(v.y);
    o.z = (short)f2bf(v.z); o.w = (short)f2bf(v.w);
    ((short4*)out)[i] = o;
}

// ---------- W[K][N] fp32 -> Wt[N][K] bf16 ----------
__global__ __launch_bounds__(256) void transpose_kernel(const float* __restrict__ W,
                                                        short* __restrict__ Wt) {
    __shared__ float t[32][33];
    int r0 = blockIdx.y * 32, c0 = blockIdx.x * 32;
    int tr = threadIdx.x >> 3;
    int tc = (threadIdx.x & 7) * 4;
    float4 v = *(const float4*)&W[(r0 + tr) * DMODEL + c0 + tc];
    t[tr][tc + 0] = v.x; t[tr][tc + 1] = v.y; t[tr][tc + 2] = v.z; t[tr][tc + 3] = v.w;
    __syncthreads();
    short4 o;
    o.x = (short)f2bf(t[tc + 0][tr]);
    o.y = (short)f2bf(t[tc + 1][tr]);
    o.z = (short)f2bf(t[tc + 2][tr]);
    o.w = (short)f2bf(t[tc + 3][tr]);
    *(short4*)&Wt[(c0 + tr) * DMODEL + r0 + tc] = o;
}

// ---------- 128x128 tile bf16 GEMM: C[M][N] = A[M][K] * Bt[N][K]^T (+bias) ----------
template<int MODE>
__global__ __launch_bounds__(256) void gemm_kernel(
    const short* __restrict__ A, const short* __restrict__ Bt,
    const float* __restrict__ b0, const float* __restrict__ b1, const float* __restrict__ b2,
    short* __restrict__ Qb, short* __restrict__ Kb, short* __restrict__ Vtb,
    float* __restrict__ Cout)
{
    __shared__ short As[128 * 72];
    __shared__ short Bs[128 * 72];
    const int K = DMODEL;
    int m0 = blockIdx.y * 128, n0 = blockIdx.x * 128;
    int tid = threadIdx.x, lane = tid & 63, wid = tid >> 6;
    int wm = (wid >> 1) * 64, wn = (wid & 1) * 64;

    f32x4 acc[4][4];
    #pragma unroll
    for (int i = 0; i < 4; i++)
        #pragma unroll
        for (int j = 0; j < 4; j++) acc[i][j] = (f32x4){0.f, 0.f, 0.f, 0.f};

    for (int kt = 0; kt < K; kt += 64) {
        #pragma unroll
        for (int i = 0; i < 4; ++i) {
            int ch = tid + 256 * i;
            int row = ch >> 3, c8 = (ch & 7) * 8;
            *(short8*)&As[row * 72 + c8] = *(const short8*)&A[(m0 + row) * K + kt + c8];
            *(short8*)&Bs[row * 72 + c8] = *(const short8*)&Bt[(n0 + row) * K + kt + c8];
        }
        __syncthreads();
        #pragma unroll
        for (int kk = 0; kk < 2; ++kk) {
            int ko = kk * 32 + (lane >> 4) * 8;
            short8 af[4], bfv[4];
            #pragma unroll
            for (int i = 0; i < 4; i++)
                af[i] = *(const short8*)&As[(wm + i * 16 + (lane & 15)) * 72 + ko];
            #pragma unroll
            for (int j = 0; j < 4; j++)
                bfv[j] = *(const short8*)&Bs[(wn + j * 16 + (lane & 15)) * 72 + ko];
            #pragma unroll
            for (int i = 0; i < 4; i++)
                #pragma unroll
                for (int j = 0; j < 4; j++)
                    acc[i][j] = __builtin_amdgcn_mfma_f32_16x16x32_bf16(af[i], bfv[j], acc[i][j], 0, 0, 0);
        }
        __syncthreads();
    }

    #pragma unroll
    for (int i = 0; i < 4; i++) {
        #pragma unroll
        for (int j = 0; j < 4; j++) {
            int col = n0 + wn + j * 16 + (lane & 15);
            #pragma unroll
            for (int r = 0; r < 4; r++) {
                int row = m0 + wm + i * 16 + (lane >> 4) * 4 + r;
                float v = acc[i][j][r];
                if (MODE == 0) {
                    int seg = col >> 10, c = col & 1023;
                    const float* bp = (seg == 0) ? b0 : (seg == 1 ? b1 : b2);
                    v += bp[c];
                    unsigned short bv = f2bf(v);
                    int hh = c >> 6, d = c & 63, bb = row >> 11, s = row & 2047;
                    if (seg == 0)      Qb [(((bb * NH + hh) * SEQ) + s) * DK + d] = (short)bv;
                    else if (seg == 1) Kb [(((bb * NH + hh) * SEQ) + s) * DK + d] = (short)bv;
                    else               Vtb[(((bb * NH + hh) * DK) + d) * SEQ + s] = (short)bv;
                } else {
                    Cout[row * DMODEL + col] = v + b0[col];
                }
            }
        }
    }
}

// ---------- flash attention, swapped-QK^T 32x32 structure ----------
// 4 waves/block, 32 q-rows/wave (128 q/block), KV tiles of 64.
// K tile LDS [kv][d] and Vt tile LDS [d][kv], both XOR-swizzled (row&7)<<4.
__global__ __launch_bounds__(256) void attn_kernel(
    const short* __restrict__ Qb, const short* __restrict__ Kb,
    const short* __restrict__ Vtb, short* __restrict__ AOb)
{
    __shared__ __align__(16) short Ks[64 * 64];
    __shared__ __align__(16) short Vs[64 * 64];
    char* ksb = (char*)Ks;
    char* vsb = (char*)Vs;

    // XCD-aware swizzle: 16 consecutive work items share one (b,h) -> same XCD
    int bid = blockIdx.x;                       // 0..1023
    int wk = (bid & 7) * 128 + (bid >> 3);
    int qi = wk & 15, bh = wk >> 4;
    int h = bh & (NH - 1), b = bh >> 4;
    int q0 = qi * 128;

    int tid = threadIdx.x, lane = tid & 63, wid = tid >> 6;
    int hi = lane >> 5, l31 = lane & 31, l7 = lane & 7;
    const short* Qp = Qb + (size_t)bh * SEQ * DK;
    const short* Kp = Kb + (size_t)bh * SEQ * DK;
    const short* Vp = Vtb + (size_t)bh * DK * SEQ;

    // Q fragments (B-operand of swapped QK^T): lane holds Q[q=l31][ks*16+hi*8+j]
    short8 qf[4];
    #pragma unroll
    for (int ks = 0; ks < 4; ks++)
        qf[ks] = *(const short8*)&Qp[(q0 + wid * 32 + l31) * DK + ks * 16 + hi * 8];

    f32x16 ot0, ot1;   // O^T accumulators: d rows 0-31 / 32-63, col q = l31
    #pragma unroll
    for (int r = 0; r < 16; r++) { ot0[r] = 0.f; ot1[r] = 0.f; }
    float mrun = -1e30f, lrun = 0.f;

    int srow = tid >> 3, ssl = tid & 7;   // staging: 256 threads x 2 chunks
    // stage tile 0
    #pragma unroll
    for (int i = 0; i < 2; i++) {
        int row = srow + 32 * i;
        *(short8*)(ksb + ((row * 128 + ssl * 16) ^ ((row & 7) << 4))) =
            *(const short8*)&Kp[row * DK + ssl * 8];
        *(short8*)(vsb + ((row * 128 + ssl * 16) ^ ((row & 7) << 4))) =
            *(const short8*)&Vp[row * SEQ + ssl * 8];
    }
    __syncthreads();

    const int NT = SEQ / 64;
    for (int t = 0; t < NT; ++t) {
        // T14: prefetch next tile into regs (latency hides under compute)
        short8 nk[2], nv[2];
        if (t + 1 < NT) {
            int kv0n = (t + 1) * 64;
            #pragma unroll
            for (int i = 0; i < 2; i++) {
                int row = srow + 32 * i;
                nk[i] = *(const short8*)&Kp[(kv0n + row) * DK + ssl * 8];
                nv[i] = *(const short8*)&Vp[row * SEQ + kv0n + ssl * 8];
            }
        }

        // swapped QK^T: St[c][kv'][q] ; A = K rows, B = Q^T
        f32x16 st0, st1;
        #pragma unroll
        for (int r = 0; r < 16; r++) { st0[r] = 0.f; st1[r] = 0.f; }
        __builtin_amdgcn_s_setprio(1);
        #pragma unroll
        for (int ks = 0; ks < 4; ks++) {
            short8 kf0 = *(const short8*)(ksb + (((l31) * 128 + ks * 32 + hi * 16) ^ (l7 << 4)));
            short8 kf1 = *(const short8*)(ksb + (((32 + l31) * 128 + ks * 32 + hi * 16) ^ (l7 << 4)));
            st0 = __builtin_amdgcn_mfma_f32_32x32x16_bf16(kf0, qf[ks], st0, 0, 0, 0);
            st1 = __builtin_amdgcn_mfma_f32_32x32x16_bf16(kf1, qf[ks], st1, 0, 0, 0);
        }
        __builtin_amdgcn_s_setprio(0);

        // online softmax (lane-local; row q = l31 shared by lane pair l/l+32)
        const float SCL = 0.125f;  // 1/sqrt(dk)
        #pragma unroll
        for (int r = 0; r < 16; r++) { st0[r] *= SCL; st1[r] *= SCL; }
        float mx[16];
        #pragma unroll
        for (int r = 0; r < 16; r++) mx[r] = fmaxf(st0[r], st1[r]);
        #pragma unroll
        for (int s = 8; s > 0; s >>= 1)
            #pragma unroll
            for (int r = 0; r < 8; r++) if (r < s) mx[r] = fmaxf(mx[r], mx[r + s]);
        float mt = fmaxf(mx[0], __shfl_xor(mx[0], 32, 64));
        // T13 defer-max: only rescale when a row grew by > 8
        if (!__all(mt - mrun <= 8.f)) {
            float mn = fmaxf(mrun, mt);
            float al = __expf(mrun - mn);
            lrun *= al;
            #pragma unroll
            for (int r = 0; r < 16; r++) { ot0[r] *= al; ot1[r] *= al; }
            mrun = mn;
        }
        float sm[16];
        #pragma unroll
        for (int r = 0; r < 16; r++) {
            st0[r] = __expf(st0[r] - mrun);
            st1[r] = __expf(st1[r] - mrun);
            sm[r] = st0[r] + st1[r];
        }
        #pragma unroll
        for (int s = 8; s > 0; s >>= 1)
            #pragma unroll
            for (int r = 0; r < 8; r++) if (r < s) sm[r] += sm[r + s];
        lrun += sm[0] + __shfl_xor(sm[0], 32, 64);

        // T12: in-register P -> bf16 A/B-fragments. w[m] covers kvc = 8m+4hi+{0..3}.
        unsigned w0[8], w1[8];
        #pragma unroll
        for (int m = 0; m < 4; m++) {
            w0[m * 2]     = pk2(st0[4 * m], st0[4 * m + 1]);
            w0[m * 2 + 1] = pk2(st0[4 * m + 2], st0[4 * m + 3]);
            w1[m * 2]     = pk2(st1[4 * m], st1[4 * m + 1]);
            w1[m * 2 + 1] = pk2(st1[4 * m + 2], st1[4 * m + 3]);
        }
        short8 pf[4];
        #pragma unroll
        for (int pp = 0; pp < 2; pp++) {
            {   // chunk 0 -> ks = pp
                unsigned o0 = hi ? w0[(2 * pp + 1) * 2]     : w0[(2 * pp) * 2];
                unsigned o1 = hi ? w0[(2 * pp + 1) * 2 + 1] : w0[(2 * pp) * 2 + 1];
                unsigned s0 = hi ? w0[(2 * pp) * 2]         : w0[(2 * pp + 1) * 2];
                unsigned s1 = hi ? w0[(2 * pp) * 2 + 1]     : w0[(2 * pp + 1) * 2 + 1];
                unsigned r0 = (unsigned)__shfl_xor((int)s0, 32, 64);
                unsigned r1 = (unsigned)__shfl_xor((int)s1, 32, 64);
                Frag f;
                f.u[0] = hi ? r0 : o0; f.u[1] = hi ? r1 : o1;
                f.u[2] = hi ? o0 : r0; f.u[3] = hi ? o1 : r1;
                pf[pp] = f.s8;
            }
            {   // chunk 1 -> ks = 2 + pp
                unsigned o0 = hi ? w1[(2 * pp + 1) * 2]     : w1[(2 * pp) * 2];
                unsigned o1 = hi ? w1[(2 * pp + 1) * 2 + 1] : w1[(2 * pp) * 2 + 1];
                unsigned s0 = hi ? w1[(2 * pp) * 2]         : w1[(2 * pp + 1) * 2];
                unsigned s1 = hi ? w1[(2 * pp) * 2 + 1]     : w1[(2 * pp + 1) * 2 + 1];
                unsigned r0 = (unsigned)__shfl_xor((int)s0, 32, 64);
                unsigned r1 = (unsigned)__shfl_xor((int)s1, 32, 64);
                Frag f;
                f.u[0] = hi ? r0 : o0; f.u[1] = hi ? r1 : o1;
                f.u[2] = hi ? o0 : r0; f.u[3] = hi ? o1 : r1;
                pf[2 + pp] = f.s8;
            }
        }

        // transposed PV: O^T[d][q] += V^T * P^T   (A = V^T rows = d, B cols = q)
        __builtin_amdgcn_s_setprio(1);
        #pragma unroll
        for (int ks = 0; ks < 4; ks++) {
            short8 vf0 = *(const short8*)(vsb + (((l31) * 128 + ks * 32 + hi * 16) ^ (l7 << 4)));
            short8 vf1 = *(const short8*)(vsb + (((32 + l31) * 128 + ks * 32 + hi * 16) ^ (l7 << 4)));
            ot0 = __builtin_amdgcn_mfma_f32_32x32x16_bf16(vf0, pf[ks], ot0, 0, 0, 0);
            ot1 = __builtin_amdgcn_mfma_f32_32x32x16_bf16(vf1, pf[ks], ot1, 0, 0, 0);
        }
        __builtin_amdgcn_s_setprio(0);

        __syncthreads();
        if (t + 1 < NT) {
            #pragma unroll
            for (int i = 0; i < 2; i++) {
                int row = srow + 32 * i;
                *(short8*)(ksb + ((row * 128 + ssl * 16) ^ ((row & 7) << 4))) = nk[i];
                *(short8*)(vsb + ((row * 128 + ssl * 16) ^ ((row & 7) << 4))) = nv[i];
            }
        }
        __syncthreads();
    }

    // epilogue: normalize + store O[q][d] as bf16 into AOb[b*SEQ+s][h*64+d]
    float inv = 1.f / lrun;
    int srow_q = b * SEQ + q0 + wid * 32 + l31;
    short* outp = AOb + (size_t)srow_q * DMODEL + h * DK;
    #pragma unroll
    for (int g = 0; g < 4; g++) {
        int d0 = 8 * g + 4 * hi;
        uint2 u;
        u.x = pk2(ot0[4 * g] * inv, ot0[4 * g + 1] * inv);
        u.y = pk2(ot0[4 * g + 2] * inv, ot0[4 * g + 3] * inv);
        *(uint2*)&outp[d0] = u;
        uint2 v2;
        v2.x = pk2(ot1[4 * g] * inv, ot1[4 * g + 1] * inv);
        v2.y = pk2(ot1[4 * g + 2] * inv, ot1[4 * g + 3] * inv);
        *(uint2*)&outp[32 + d0] = v2;
    }
}

extern "C" void kernel_launch(void* const* d_in, const int* in_sizes, int n_in,
                              void* d_out, int out_size, void* d_ws, size_t ws_size,
                              hipStream_t stream)
{
    const float* x  = (const float*)d_in[0];
    const float* Wq = (const float*)d_in[1];
    const float* bq = (const float*)d_in[2];
    const float* Wk = (const float*)d_in[3];
    const float* bk = (const float*)d_in[4];
    const float* Wv = (const float*)d_in[5];
    const float* bv = (const float*)d_in[6];
    const float* Wo = (const float*)d_in[7];
    const float* bo = (const float*)d_in[8];
    float* out = (float*)d_out;

    char* w = (char*)d_ws;
    short* xb    = (short*)w; w += (size_t)MTOT * DMODEL * 2;
    short* Wqkvt = (short*)w; w += (size_t)3 * DMODEL * DMODEL * 2;
    short* Wot   = (short*)w; w += (size_t)DMODEL * DMODEL * 2;
    short* Qb    = (short*)w; w += (size_t)MTOT * DMODEL * 2;
    short* Kb    = (short*)w; w += (size_t)MTOT * DMODEL * 2;
    short* Vtb   = (short*)w; w += (size_t)MTOT * DMODEL * 2;
    short* AOb   = (short*)w; w += (size_t)MTOT * DMODEL * 2;

    cvt_kernel<<<(MTOT * DMODEL / 4 + 255) / 256, 256, 0, stream>>>(x, xb, MTOT * DMODEL / 4);

    dim3 tg(32, 32);
    transpose_kernel<<<tg, 256, 0, stream>>>(Wq, Wqkvt);
    transpose_kernel<<<tg, 256, 0, stream>>>(Wk, Wqkvt + DMODEL * DMODEL);
    transpose_kernel<<<tg, 256, 0, stream>>>(Wv, Wqkvt + 2 * DMODEL * DMODEL);
    transpose_kernel<<<tg, 256, 0, stream>>>(Wo, Wot);

    gemm_kernel<0><<<dim3(3 * DMODEL / 128, MTOT / 128), 256, 0, stream>>>(
        xb, Wqkvt, bq, bk, bv, Qb, Kb, Vtb, nullptr);

    attn_kernel<<<dim3(SEQ / 128 * NH * NB), 256, 0, stream>>>(Qb, Kb, Vtb, AOb);

    gemm_kernel<1><<<dim3(DMODEL / 128, MTOT / 128), 256, 0, stream>>>(
        AOb, Wot, bo, nullptr, nullptr, nullptr, nullptr, nullptr, out);
}

// Round 4
// 226.337 us; speedup vs baseline: 1.9393x; 1.1458x over previous
//
#include <hip/hip_runtime.h>

// MHA forward, bf16-MFMA pipeline.
// ws: xb(16M) | Wqkv_t(6M) | Wo_t(2M) | Q(16M) | K(16M) | Vt(16M) | AO(16M)

typedef short short8 __attribute__((ext_vector_type(8)));
typedef float f32x4 __attribute__((ext_vector_type(4)));
typedef float f32x16 __attribute__((ext_vector_type(16)));

#define DMODEL 1024
#define NH 16
#define DK 64
#define SEQ 2048
#define NB 4
#define MTOT (NB*SEQ)   // 8192
// 1/sqrt(dk) * log2(e)  — folded into K at projection time; softmax runs in exp2 domain
#define KSCALE 0.18033688f

__device__ __forceinline__ unsigned short f2bf(float f) {
    union { float f; unsigned u; } v; v.f = f;
    unsigned r = (v.u + 0x7FFFu + ((v.u >> 16) & 1u)) >> 16;  // RNE
    return (unsigned short)r;
}

__device__ __forceinline__ unsigned pk2(float a, float b) {
    unsigned r;
    asm("v_cvt_pk_bf16_f32 %0, %1, %2" : "=v"(r) : "v"(a), "v"(b));
    return r;
}

__device__ __forceinline__ float exp2a(float x) {
    float r; asm("v_exp_f32 %0, %1" : "=v"(r) : "v"(x)); return r;
}

__device__ __forceinline__ float max3a(float a, float b, float c) {
    float r; asm("v_max3_f32 %0, %1, %2, %3" : "=v"(r) : "v"(a), "v"(b), "v"(c)); return r;
}

// v_permlane32_swap_b32: vdst lanes 32-63 <-> vsrc lanes 0-31 (both modified)
__device__ __forceinline__ void plswap(unsigned &a, unsigned &b) {
    asm volatile("v_permlane32_swap_b32 %0, %1" : "+v"(a), "+v"(b));
}

// async global->LDS, 16B per lane; lds dest is wave-uniform base (+lane*16)
__device__ __forceinline__ void gload16(const short* g, short* l) {
    __builtin_amdgcn_global_load_lds(
        (const __attribute__((address_space(1))) unsigned*)(const void*)g,
        (__attribute__((address_space(3))) unsigned*)(void*)l,
        16, 0, 0);
}

union Frag { short8 s8; unsigned u[4]; };

// ---------- fp32 -> bf16 convert ----------
__global__ __launch_bounds__(256) void cvt_kernel(const float* __restrict__ in,
                                                  short* __restrict__ out, int n4) {
    int i = blockIdx.x * 256 + threadIdx.x;
    if (i >= n4) return;
    float4 v = ((const float4*)in)[i];
    short4 o;
    o.x = (short)f2bf(v.x); o.y = (short)f2bf(v.y);
    o.z = (short)f2bf(v.z); o.w = (short)f2bf(v.w);
    ((short4*)out)[i] = o;
}

// ---------- W[K][N] fp32 -> Wt[N][K] bf16 ----------
__global__ __launch_bounds__(256) void transpose_kernel(const float* __restrict__ W,
                                                        short* __restrict__ Wt) {
    __shared__ float t[32][33];
    int r0 = blockIdx.y * 32, c0 = blockIdx.x * 32;
    int tr = threadIdx.x >> 3;
    int tc = (threadIdx.x & 7) * 4;
    float4 v = *(const float4*)&W[(r0 + tr) * DMODEL + c0 + tc];
    t[tr][tc + 0] = v.x; t[tr][tc + 1] = v.y; t[tr][tc + 2] = v.z; t[tr][tc + 3] = v.w;
    __syncthreads();
    short4 o;
    o.x = (short)f2bf(t[tc + 0][tr]);
    o.y = (short)f2bf(t[tc + 1][tr]);
    o.z = (short)f2bf(t[tc + 2][tr]);
    o.w = (short)f2bf(t[tc + 3][tr]);
    *(short4*)&Wt[(c0 + tr) * DMODEL + r0 + tc] = o;
}

// ---------- 128x128 bf16 GEMM, global_load_lds staging (m97 structure) ----------
// LDS linear [128][64]; source columns pre-swizzled by (row&7); reads XOR-swizzled.
template<int MODE>
__global__ __launch_bounds__(256) void gemm_kernel(
    const short* __restrict__ A, const short* __restrict__ Bt,
    const float* __restrict__ b0, const float* __restrict__ b1, const float* __restrict__ b2,
    short* __restrict__ Qb, short* __restrict__ Kb, short* __restrict__ Vtb,
    float* __restrict__ Cout)
{
    __shared__ __align__(16) short As[128 * 64];
    __shared__ __align__(16) short Bs[128 * 64];
    const int K = DMODEL;
    int m0 = blockIdx.y * 128, n0 = blockIdx.x * 128;
    int tid = threadIdx.x, lane = tid & 63, wid = tid >> 6;
    int wm = (wid >> 1) * 64, wn = (wid & 1) * 64;

    // staging: instr (w,i) covers rows 8w+32i + (lane>>3); lane source col chunk (lane&7)^(lane>>3)
    int srow = 8 * wid + (lane >> 3);
    int scol = ((lane & 7) ^ (lane >> 3)) * 8;
    const short* aSrc = A + (size_t)(m0 + srow) * K + scol;
    const short* bSrc = Bt + (size_t)(n0 + srow) * K + scol;

    f32x4 acc[4][4];
    #pragma unroll
    for (int i = 0; i < 4; i++)
        #pragma unroll
        for (int j = 0; j < 4; j++) acc[i][j] = (f32x4){0.f, 0.f, 0.f, 0.f};

    for (int kt = 0; kt < K; kt += 64) {
        #pragma unroll
        for (int i = 0; i < 4; ++i) {
            gload16(aSrc + (size_t)(32 * i) * K + kt, &As[(8 * wid + 32 * i) * 64]);
            gload16(bSrc + (size_t)(32 * i) * K + kt, &Bs[(8 * wid + 32 * i) * 64]);
        }
        __syncthreads();
        #pragma unroll
        for (int kk = 0; kk < 2; ++kk) {
            int ko = kk * 32 + (lane >> 4) * 8;
            short8 af[4], bfv[4];
            #pragma unroll
            for (int i = 0; i < 4; i++) {
                int r = wm + i * 16 + (lane & 15);
                af[i] = *(const short8*)&As[(r * 64 + ko) ^ ((r & 7) << 3)];
            }
            #pragma unroll
            for (int j = 0; j < 4; j++) {
                int r = wn + j * 16 + (lane & 15);
                bfv[j] = *(const short8*)&Bs[(r * 64 + ko) ^ ((r & 7) << 3)];
            }
            #pragma unroll
            for (int i = 0; i < 4; i++)
                #pragma unroll
                for (int j = 0; j < 4; j++)
                    acc[i][j] = __builtin_amdgcn_mfma_f32_16x16x32_bf16(af[i], bfv[j], acc[i][j], 0, 0, 0);
        }
        __syncthreads();
    }

    #pragma unroll
    for (int i = 0; i < 4; i++) {
        #pragma unroll
        for (int j = 0; j < 4; j++) {
            int col = n0 + wn + j * 16 + (lane & 15);
            #pragma unroll
            for (int r = 0; r < 4; r++) {
                int row = m0 + wm + i * 16 + (lane >> 4) * 4 + r;
                float v = acc[i][j][r];
                if (MODE == 0) {
                    int seg = col >> 10, c = col & 1023;
                    const float* bp = (seg == 0) ? b0 : (seg == 1 ? b1 : b2);
                    v += bp[c];
                    if (seg == 1) v *= KSCALE;   // fold softmax scale*log2e into K
                    unsigned short bv = f2bf(v);
                    int hh = c >> 6, d = c & 63, bb = row >> 11, s = row & 2047;
                    if (seg == 0)      Qb [(((bb * NH + hh) * SEQ) + s) * DK + d] = (short)bv;
                    else if (seg == 1) Kb [(((bb * NH + hh) * SEQ) + s) * DK + d] = (short)bv;
                    else               Vtb[(((bb * NH + hh) * DK) + d) * SEQ + s] = (short)bv;
                } else {
                    Cout[row * DMODEL + col] = v + b0[col];
                }
            }
        }
    }
}

// ---------- flash attention, swapped-QK^T 32x32, exp2-domain softmax ----------
// 4 waves, 32 q/wave, KV tiles 64. Staging: round-2 proven reg-staged ds_write
// (T14 split: global->reg prefetch before compute, LDS write after barrier).
__global__ __launch_bounds__(256) void attn_kernel(
    const short* __restrict__ Qb, const short* __restrict__ Kb,
    const short* __restrict__ Vtb, short* __restrict__ AOb)
{
    __shared__ __align__(16) short Ks[64 * 64];
    __shared__ __align__(16) short Vs[64 * 64];
    char* ksb = (char*)Ks;
    char* vsb = (char*)Vs;

    int bid = blockIdx.x;                       // 0..1023
    int wk = (bid & 7) * 128 + (bid >> 3);      // XCD-contiguous work
    int qi = wk & 15, bh = wk >> 4;
    int h = bh & (NH - 1), b = bh >> 4;
    int q0 = qi * 128;

    int tid = threadIdx.x, lane = tid & 63, wid = tid >> 6;
    int hi = lane >> 5, l31 = lane & 31, l7 = lane & 7;
    const short* Qp = Qb + (size_t)bh * SEQ * DK;
    const short* Kp = Kb + (size_t)bh * SEQ * DK;
    const short* Vp = Vtb + (size_t)bh * DK * SEQ;

    // Q fragments (B-operand): lane holds Q[q=l31][ks*16+hi*8+j]
    short8 qf[4];
    #pragma unroll
    for (int ks = 0; ks < 4; ks++)
        qf[ks] = *(const short8*)&Qp[(q0 + wid * 32 + l31) * DK + ks * 16 + hi * 8];

    f32x16 ot0, ot1;
    #pragma unroll
    for (int r = 0; r < 16; r++) { ot0[r] = 0.f; ot1[r] = 0.f; }
    float mrun = -1e30f, lrun = 0.f;

    int srow = tid >> 3, ssl = tid & 7;   // staging: 256 threads x 2 chunks
    // stage tile 0
    #pragma unroll
    for (int i = 0; i < 2; i++) {
        int row = srow + 32 * i;
        *(short8*)(ksb + ((row * 128 + ssl * 16) ^ ((row & 7) << 4))) =
            *(const short8*)&Kp[row * DK + ssl * 8];
        *(short8*)(vsb + ((row * 128 + ssl * 16) ^ ((row & 7) << 4))) =
            *(const short8*)&Vp[row * SEQ + ssl * 8];
    }
    __syncthreads();

    const int NT = SEQ / 64;
    for (int t = 0; t < NT; ++t) {
        // T14: prefetch next tile into regs (latency hides under compute)
        short8 nk[2], nv[2];
        if (t + 1 < NT) {
            int kv0n = (t + 1) * 64;
            #pragma unroll
            for (int i = 0; i < 2; i++) {
                int row = srow + 32 * i;
                nk[i] = *(const short8*)&Kp[(kv0n + row) * DK + ssl * 8];
                nv[i] = *(const short8*)&Vp[row * SEQ + kv0n + ssl * 8];
            }
        }

        // swapped QK^T: St[kv][q]
        f32x16 st0, st1;
        #pragma unroll
        for (int r = 0; r < 16; r++) { st0[r] = 0.f; st1[r] = 0.f; }
        __builtin_amdgcn_s_setprio(1);
        #pragma unroll
        for (int ks = 0; ks < 4; ks++) {
            short8 kf0 = *(const short8*)(ksb + ((l31 * 128 + ks * 32 + hi * 16) ^ (l7 << 4)));
            short8 kf1 = *(const short8*)(ksb + (((32 + l31) * 128 + ks * 32 + hi * 16) ^ (l7 << 4)));
            st0 = __builtin_amdgcn_mfma_f32_32x32x16_bf16(kf0, qf[ks], st0, 0, 0, 0);
            st1 = __builtin_amdgcn_mfma_f32_32x32x16_bf16(kf1, qf[ks], st1, 0, 0, 0);
        }
        __builtin_amdgcn_s_setprio(0);

        // row max via max3 tree (32 values -> 1), then lane-pair exchange
        float m8[8];
        #pragma unroll
        for (int i = 0; i < 8; i++) m8[i] = max3a(st0[i], st0[i + 8], st1[i]);
        float m4[4];
        #pragma unroll
        for (int i = 0; i < 4; i++) m4[i] = max3a(m8[i], m8[i + 4], st1[i + 8]);
        float m2a = max3a(m4[0], m4[2], st1[12]);
        float m2b = max3a(m4[1], m4[3], st1[13]);
        float mxv = max3a(m2a, m2b, st1[14]);
        mxv = fmaxf(mxv, st1[15]);
        float mt = fmaxf(mxv, __shfl_xor(mxv, 32, 64));

        // T13 defer-max (log2 domain, threshold 11 -> P bounded by 2^11)
        if (!__all(mt - mrun <= 11.0f)) {
            float mn = fmaxf(mrun, mt);
            float al = exp2a(mrun - mn);
            lrun *= al;
            #pragma unroll
            for (int r = 0; r < 16; r++) { ot0[r] *= al; ot1[r] *= al; }
            mrun = mn;
        }
        #pragma unroll
        for (int r = 0; r < 16; r++) {
            st0[r] = exp2a(st0[r] - mrun);
            st1[r] = exp2a(st1[r] - mrun);
        }
        float s16[16];
        #pragma unroll
        for (int r = 0; r < 16; r++) s16[r] = st0[r] + st1[r];
        #pragma unroll
        for (int s = 8; s > 0; s >>= 1)
            #pragma unroll
            for (int r = 0; r < 8; r++) if (r < s) s16[r] += s16[r + s];
        lrun += s16[0] + __shfl_xor(s16[0], 32, 64);

        // T12 repack: P -> bf16 B-fragments via cvt_pk + permlane32_swap
        unsigned w0[8], w1[8];
        #pragma unroll
        for (int m = 0; m < 4; m++) {
            w0[m * 2]     = pk2(st0[4 * m], st0[4 * m + 1]);
            w0[m * 2 + 1] = pk2(st0[4 * m + 2], st0[4 * m + 3]);
            w1[m * 2]     = pk2(st1[4 * m], st1[4 * m + 1]);
            w1[m * 2 + 1] = pk2(st1[4 * m + 2], st1[4 * m + 3]);
        }
        short8 pf[4];
        #pragma unroll
        for (int ks = 0; ks < 4; ks++) {
            unsigned a0 = (ks < 2) ? w0[4 * (ks & 1) + 0] : w1[4 * (ks & 1) + 0];
            unsigned b0_ = (ks < 2) ? w0[4 * (ks & 1) + 2] : w1[4 * (ks & 1) + 2];
            unsigned a1 = (ks < 2) ? w0[4 * (ks & 1) + 1] : w1[4 * (ks & 1) + 1];
            unsigned b1_ = (ks < 2) ? w0[4 * (ks & 1) + 3] : w1[4 * (ks & 1) + 3];
            plswap(a0, b0_);
            plswap(a1, b1_);
            Frag f;
            f.u[0] = a0; f.u[1] = a1; f.u[2] = b0_; f.u[3] = b1_;
            pf[ks] = f.s8;
        }

        // transposed PV: O^T[d][q] += V^T * P^T
        __builtin_amdgcn_s_setprio(1);
        #pragma unroll
        for (int ks = 0; ks < 4; ks++) {
            short8 vf0 = *(const short8*)(vsb + ((l31 * 128 + ks * 32 + hi * 16) ^ (l7 << 4)));
            short8 vf1 = *(const short8*)(vsb + (((32 + l31) * 128 + ks * 32 + hi * 16) ^ (l7 << 4)));
            ot0 = __builtin_amdgcn_mfma_f32_32x32x16_bf16(vf0, pf[ks], ot0, 0, 0, 0);
            ot1 = __builtin_amdgcn_mfma_f32_32x32x16_bf16(vf1, pf[ks], ot1, 0, 0, 0);
        }
        __builtin_amdgcn_s_setprio(0);

        __syncthreads();
        if (t + 1 < NT) {
            #pragma unroll
            for (int i = 0; i < 2; i++) {
                int row = srow + 32 * i;
                *(short8*)(ksb + ((row * 128 + ssl * 16) ^ ((row & 7) << 4))) = nk[i];
                *(short8*)(vsb + ((row * 128 + ssl * 16) ^ ((row & 7) << 4))) = nv[i];
            }
        }
        __syncthreads();
    }

    // epilogue: normalize + store O[q][d] bf16 into AOb[b*SEQ+s][h*64+d]
    float inv = 1.f / lrun;
    int srow_q = b * SEQ + q0 + wid * 32 + l31;
    short* outp = AOb + (size_t)srow_q * DMODEL + h * DK;
    #pragma unroll
    for (int g = 0; g < 4; g++) {
        int d0 = 8 * g + 4 * hi;
        uint2 u;
        u.x = pk2(ot0[4 * g] * inv, ot0[4 * g + 1] * inv);
        u.y = pk2(ot0[4 * g + 2] * inv, ot0[4 * g + 3] * inv);
        *(uint2*)&outp[d0] = u;
        uint2 v2;
        v2.x = pk2(ot1[4 * g] * inv, ot1[4 * g + 1] * inv);
        v2.y = pk2(ot1[4 * g + 2] * inv, ot1[4 * g + 3] * inv);
        *(uint2*)&outp[32 + d0] = v2;
    }
}

extern "C" void kernel_launch(void* const* d_in, const int* in_sizes, int n_in,
                              void* d_out, int out_size, void* d_ws, size_t ws_size,
                              hipStream_t stream)
{
    const float* x  = (const float*)d_in[0];
    const float* Wq = (const float*)d_in[1];
    const float* bq = (const float*)d_in[2];
    const float* Wk = (const float*)d_in[3];
    const float* bk = (const float*)d_in[4];
    const float* Wv = (const float*)d_in[5];
    const float* bv = (const float*)d_in[6];
    const float* Wo = (const float*)d_in[7];
    const float* bo = (const float*)d_in[8];
    float* out = (float*)d_out;

    char* w = (char*)d_ws;
    short* xb    = (short*)w; w += (size_t)MTOT * DMODEL * 2;
    short* Wqkvt = (short*)w; w += (size_t)3 * DMODEL * DMODEL * 2;
    short* Wot   = (short*)w; w += (size_t)DMODEL * DMODEL * 2;
    short* Qb    = (short*)w; w += (size_t)MTOT * DMODEL * 2;
    short* Kb    = (short*)w; w += (size_t)MTOT * DMODEL * 2;
    short* Vtb   = (short*)w; w += (size_t)MTOT * DMODEL * 2;
    short* AOb   = (short*)w; w += (size_t)MTOT * DMODEL * 2;

    cvt_kernel<<<(MTOT * DMODEL / 4 + 255) / 256, 256, 0, stream>>>(x, xb, MTOT * DMODEL / 4);

    dim3 tg(32, 32);
    transpose_kernel<<<tg, 256, 0, stream>>>(Wq, Wqkvt);
    transpose_kernel<<<tg, 256, 0, stream>>>(Wk, Wqkvt + DMODEL * DMODEL);
    transpose_kernel<<<tg, 256, 0, stream>>>(Wv, Wqkvt + 2 * DMODEL * DMODEL);
    transpose_kernel<<<tg, 256, 0, stream>>>(Wo, Wot);

    gemm_kernel<0><<<dim3(3 * DMODEL / 128, MTOT / 128), 256, 0, stream>>>(
        xb, Wqkvt, bq, bk, bv, Qb, Kb, Vtb, nullptr);

    attn_kernel<<<dim3(SEQ / 128 * NH * NB), 256, 0, stream>>>(Qb, Kb, Vtb, AOb);

    gemm_kernel<1><<<dim3(DMODEL / 128, MTOT / 128), 256, 0, stream>>>(
        AOb, Wot, bo, nullptr, nullptr, nullptr, nullptr, nullptr, out);
}

// Round 5
// 224.334 us; speedup vs baseline: 1.9567x; 1.0089x over previous
//
#include <hip/hip_runtime.h>

// MHA forward, bf16-MFMA pipeline.
// ws: xb(16M) | Wqkv_t(6M) | Wo_t(2M) | Q(16M) | K(16M) | Vt(16M) | AO(16M)

typedef short short8 __attribute__((ext_vector_type(8)));
typedef float f32x4 __attribute__((ext_vector_type(4)));
typedef float f32x16 __attribute__((ext_vector_type(16)));

#define DMODEL 1024
#define NH 16
#define DK 64
#define SEQ 2048
#define NB 4
#define MTOT (NB*SEQ)   // 8192
// 1/sqrt(dk) * log2(e)  — folded into K at projection time; softmax runs in exp2 domain
#define KSCALE 0.18033688f

__device__ __forceinline__ unsigned short f2bf(float f) {
    union { float f; unsigned u; } v; v.f = f;
    unsigned r = (v.u + 0x7FFFu + ((v.u >> 16) & 1u)) >> 16;  // RNE
    return (unsigned short)r;
}

__device__ __forceinline__ unsigned pk2(float a, float b) {
    unsigned r;
    asm("v_cvt_pk_bf16_f32 %0, %1, %2" : "=v"(r) : "v"(a), "v"(b));
    return r;
}

__device__ __forceinline__ float exp2a(float x) {
    float r; asm("v_exp_f32 %0, %1" : "=v"(r) : "v"(x)); return r;
}

__device__ __forceinline__ float max3a(float a, float b, float c) {
    float r; asm("v_max3_f32 %0, %1, %2, %3" : "=v"(r) : "v"(a), "v"(b), "v"(c)); return r;
}

// v_permlane32_swap_b32: vdst lanes 32-63 <-> vsrc lanes 0-31 (both modified)
__device__ __forceinline__ void plswap(unsigned &a, unsigned &b) {
    asm volatile("v_permlane32_swap_b32 %0, %1" : "+v"(a), "+v"(b));
}

// lane-pair (l <-> l+32) reductions via permlane32_swap on a forced copy.
// After swap: x = [v0:31|v0:31], y = [v32:63|v32:63]; op(x,y) = pairwise result on every lane.
__device__ __forceinline__ float pairmax32(float v) {
    float x = v, y;
    asm volatile("v_mov_b32 %0, %1" : "=v"(y) : "v"(v));
    asm volatile("v_permlane32_swap_b32 %0, %1" : "+v"(x), "+v"(y));
    return fmaxf(x, y);
}
__device__ __forceinline__ float pairsum32(float v) {
    float x = v, y;
    asm volatile("v_mov_b32 %0, %1" : "=v"(y) : "v"(v));
    asm volatile("v_permlane32_swap_b32 %0, %1" : "+v"(x), "+v"(y));
    return x + y;
}

// async global->LDS, 16B per lane; lds dest is wave-uniform base (+lane*16)
__device__ __forceinline__ void gload16(const short* g, short* l) {
    __builtin_amdgcn_global_load_lds(
        (const __attribute__((address_space(1))) unsigned*)(const void*)g,
        (__attribute__((address_space(3))) unsigned*)(void*)l,
        16, 0, 0);
}

union Frag { short8 s8; unsigned u[4]; };

// ---------- fused prep: x fp32->bf16 convert + 4x W transpose ----------
// blocks [0, NCVT): cvt;  blocks [NCVT, NCVT+4096): 32x32 transpose tiles.
#define NCVT (MTOT * DMODEL / 4 / 256)   // 8192
__global__ __launch_bounds__(256) void prep_kernel(
    const float* __restrict__ x, short* __restrict__ xb,
    const float* __restrict__ Wq, const float* __restrict__ Wk,
    const float* __restrict__ Wv, const float* __restrict__ Wo,
    short* __restrict__ Wqkvt, short* __restrict__ Wot)
{
    __shared__ float t[32][33];
    int bid = blockIdx.x;
    if (bid < NCVT) {
        int i = bid * 256 + threadIdx.x;
        float4 v = ((const float4*)x)[i];
        short4 o;
        o.x = (short)f2bf(v.x); o.y = (short)f2bf(v.y);
        o.z = (short)f2bf(v.z); o.w = (short)f2bf(v.w);
        ((short4*)xb)[i] = o;
        return;
    }
    int wb = bid - NCVT;                 // 0..4095
    int widx = wb >> 10, tile = wb & 1023;
    const float* W = (widx == 0) ? Wq : (widx == 1) ? Wk : (widx == 2) ? Wv : Wo;
    short* dst = (widx < 3) ? (Wqkvt + (size_t)widx * DMODEL * DMODEL) : Wot;
    int r0 = (tile >> 5) * 32, c0 = (tile & 31) * 32;
    int tr = threadIdx.x >> 3;
    int tc = (threadIdx.x & 7) * 4;
    float4 v = *(const float4*)&W[(r0 + tr) * DMODEL + c0 + tc];
    t[tr][tc + 0] = v.x; t[tr][tc + 1] = v.y; t[tr][tc + 2] = v.z; t[tr][tc + 3] = v.w;
    __syncthreads();
    short4 o;
    o.x = (short)f2bf(t[tc + 0][tr]);
    o.y = (short)f2bf(t[tc + 1][tr]);
    o.z = (short)f2bf(t[tc + 2][tr]);
    o.w = (short)f2bf(t[tc + 3][tr]);
    *(short4*)&dst[(c0 + tr) * DMODEL + r0 + tc] = o;
}

// ---------- 128x128 bf16 GEMM, global_load_lds staging (m97 structure) ----------
// LDS linear [128][64]; source columns pre-swizzled by (row&7); reads XOR-swizzled.
template<int MODE>
__global__ __launch_bounds__(256) void gemm_kernel(
    const short* __restrict__ A, const short* __restrict__ Bt,
    const float* __restrict__ b0, const float* __restrict__ b1, const float* __restrict__ b2,
    short* __restrict__ Qb, short* __restrict__ Kb, short* __restrict__ Vtb,
    float* __restrict__ Cout)
{
    __shared__ __align__(16) short As[128 * 64];
    __shared__ __align__(16) short Bs[128 * 64];
    const int K = DMODEL;
    int m0 = blockIdx.y * 128, n0 = blockIdx.x * 128;
    int tid = threadIdx.x, lane = tid & 63, wid = tid >> 6;
    int wm = (wid >> 1) * 64, wn = (wid & 1) * 64;

    // staging: instr (w,i) covers rows 8w+32i + (lane>>3); lane source col chunk (lane&7)^(lane>>3)
    int srow = 8 * wid + (lane >> 3);
    int scol = ((lane & 7) ^ (lane >> 3)) * 8;
    const short* aSrc = A + (size_t)(m0 + srow) * K + scol;
    const short* bSrc = Bt + (size_t)(n0 + srow) * K + scol;

    f32x4 acc[4][4];
    #pragma unroll
    for (int i = 0; i < 4; i++)
        #pragma unroll
        for (int j = 0; j < 4; j++) acc[i][j] = (f32x4){0.f, 0.f, 0.f, 0.f};

    for (int kt = 0; kt < K; kt += 64) {
        #pragma unroll
        for (int i = 0; i < 4; ++i) {
            gload16(aSrc + (size_t)(32 * i) * K + kt, &As[(8 * wid + 32 * i) * 64]);
            gload16(bSrc + (size_t)(32 * i) * K + kt, &Bs[(8 * wid + 32 * i) * 64]);
        }
        __syncthreads();
        #pragma unroll
        for (int kk = 0; kk < 2; ++kk) {
            int ko = kk * 32 + (lane >> 4) * 8;
            short8 af[4], bfv[4];
            #pragma unroll
            for (int i = 0; i < 4; i++) {
                int r = wm + i * 16 + (lane & 15);
                af[i] = *(const short8*)&As[(r * 64 + ko) ^ ((r & 7) << 3)];
            }
            #pragma unroll
            for (int j = 0; j < 4; j++) {
                int r = wn + j * 16 + (lane & 15);
                bfv[j] = *(const short8*)&Bs[(r * 64 + ko) ^ ((r & 7) << 3)];
            }
            #pragma unroll
            for (int i = 0; i < 4; i++)
                #pragma unroll
                for (int j = 0; j < 4; j++)
                    acc[i][j] = __builtin_amdgcn_mfma_f32_16x16x32_bf16(af[i], bfv[j], acc[i][j], 0, 0, 0);
        }
        __syncthreads();
    }

    #pragma unroll
    for (int i = 0; i < 4; i++) {
        #pragma unroll
        for (int j = 0; j < 4; j++) {
            int col = n0 + wn + j * 16 + (lane & 15);
            #pragma unroll
            for (int r = 0; r < 4; r++) {
                int row = m0 + wm + i * 16 + (lane >> 4) * 4 + r;
                float v = acc[i][j][r];
                if (MODE == 0) {
                    int seg = col >> 10, c = col & 1023;
                    const float* bp = (seg == 0) ? b0 : (seg == 1 ? b1 : b2);
                    v += bp[c];
                    if (seg == 1) v *= KSCALE;   // fold softmax scale*log2e into K
                    unsigned short bv = f2bf(v);
                    int hh = c >> 6, d = c & 63, bb = row >> 11, s = row & 2047;
                    if (seg == 0)      Qb [(((bb * NH + hh) * SEQ) + s) * DK + d] = (short)bv;
                    else if (seg == 1) Kb [(((bb * NH + hh) * SEQ) + s) * DK + d] = (short)bv;
                    else               Vtb[(((bb * NH + hh) * DK) + d) * SEQ + s] = (short)bv;
                } else {
                    Cout[row * DMODEL + col] = v + b0[col];
                }
            }
        }
    }
}

// ---------- flash attention, swapped-QK^T 32x32, exp2-domain softmax ----------
// 4 waves, 32 q/wave, KV tiles 64. Double-buffered LDS, ONE barrier per tile.
// C-init = -mrun (softmax sub folded into MFMA). Reg-staged ds_write (proven).
__global__ __launch_bounds__(256) void attn_kernel(
    const short* __restrict__ Qb, const short* __restrict__ Kb,
    const short* __restrict__ Vtb, short* __restrict__ AOb)
{
    __shared__ __align__(16) short Ks[2][64 * 64];
    __shared__ __align__(16) short Vs[2][64 * 64];

    int bid = blockIdx.x;                       // 0..1023
    int wk = (bid & 7) * 128 + (bid >> 3);      // XCD-contiguous work
    int qi = wk & 15, bh = wk >> 4;
    int h = bh & (NH - 1), b = bh >> 4;
    int q0 = qi * 128;

    int tid = threadIdx.x, lane = tid & 63, wid = tid >> 6;
    int hi = lane >> 5, l31 = lane & 31, l7 = lane & 7;
    const short* Qp = Qb + (size_t)bh * SEQ * DK;
    const short* Kp = Kb + (size_t)bh * SEQ * DK;
    const short* Vp = Vtb + (size_t)bh * DK * SEQ;

    // Q fragments (B-operand): lane holds Q[q=l31][ks*16+hi*8+j]
    short8 qf[4];
    #pragma unroll
    for (int ks = 0; ks < 4; ks++)
        qf[ks] = *(const short8*)&Qp[(q0 + wid * 32 + l31) * DK + ks * 16 + hi * 8];

    f32x16 ot0, ot1;
    #pragma unroll
    for (int r = 0; r < 16; r++) { ot0[r] = 0.f; ot1[r] = 0.f; }
    float mrun = 0.f, lrun = 0.f;   // mrun starts 0; defer-max rescales up when needed

    int srow = tid >> 3, ssl = tid & 7;   // staging: 256 threads x 2 chunks
    // stage tile 0 into buffer 0
    #pragma unroll
    for (int i = 0; i < 2; i++) {
        int row = srow + 32 * i;
        *(short8*)((char*)Ks[0] + ((row * 128 + ssl * 16) ^ ((row & 7) << 4))) =
            *(const short8*)&Kp[row * DK + ssl * 8];
        *(short8*)((char*)Vs[0] + ((row * 128 + ssl * 16) ^ ((row & 7) << 4))) =
            *(const short8*)&Vp[row * SEQ + ssl * 8];
    }
    __syncthreads();

    const int NT = SEQ / 64;
    for (int t = 0; t < NT; ++t) {
        int cur = t & 1;
        const char* kb = (const char*)Ks[cur];
        const char* vb = (const char*)Vs[cur];

        // T14: prefetch next tile into regs (latency hides under compute)
        short8 nk[2], nv[2];
        if (t + 1 < NT) {
            int kv0n = (t + 1) * 64;
            #pragma unroll
            for (int i = 0; i < 2; i++) {
                int row = srow + 32 * i;
                nk[i] = *(const short8*)&Kp[(kv0n + row) * DK + ssl * 8];
                nv[i] = *(const short8*)&Vp[row * SEQ + kv0n + ssl * 8];
            }
        }

        // swapped QK^T: St[kv][q], C-init = -mrun so st = S - mrun directly
        float negm = -mrun;
        f32x16 st0, st1;
        #pragma unroll
        for (int r = 0; r < 16; r++) { st0[r] = negm; st1[r] = negm; }
        __builtin_amdgcn_s_setprio(1);
        #pragma unroll
        for (int ks = 0; ks < 4; ks++) {
            short8 kf0 = *(const short8*)(kb + ((l31 * 128 + ks * 32 + hi * 16) ^ (l7 << 4)));
            short8 kf1 = *(const short8*)(kb + (((32 + l31) * 128 + ks * 32 + hi * 16) ^ (l7 << 4)));
            st0 = __builtin_amdgcn_mfma_f32_32x32x16_bf16(kf0, qf[ks], st0, 0, 0, 0);
            st1 = __builtin_amdgcn_mfma_f32_32x32x16_bf16(kf1, qf[ks], st1, 0, 0, 0);
        }
        __builtin_amdgcn_s_setprio(0);

        // row max via max3 tree (32 rel-values -> 1), then lane-pair exchange
        float m8[8];
        #pragma unroll
        for (int i = 0; i < 8; i++) m8[i] = max3a(st0[i], st0[i + 8], st1[i]);
        float m4[4];
        #pragma unroll
        for (int i = 0; i < 4; i++) m4[i] = max3a(m8[i], m8[i + 4], st1[i + 8]);
        float m2a = max3a(m4[0], m4[2], st1[12]);
        float m2b = max3a(m4[1], m4[3], st1[13]);
        float mxv = max3a(m2a, m2b, st1[14]);
        mxv = fmaxf(mxv, st1[15]);
        float mt = pairmax32(mxv);   // relative to mrun

        // T13 defer-max: rescale only when relative growth > 11 (P bounded by 2^11)
        if (!__all(mt <= 11.0f)) {
            float d = fmaxf(mt, 0.f);
            float al = exp2a(-d);
            lrun *= al;
            #pragma unroll
            for (int r = 0; r < 16; r++) {
                ot0[r] *= al; ot1[r] *= al;
                st0[r] -= d; st1[r] -= d;
            }
            mrun += d;
        }
        #pragma unroll
        for (int r = 0; r < 16; r++) {
            st0[r] = exp2a(st0[r]);
            st1[r] = exp2a(st1[r]);
        }
        float s16[16];
        #pragma unroll
        for (int r = 0; r < 16; r++) s16[r] = st0[r] + st1[r];
        #pragma unroll
        for (int s = 8; s > 0; s >>= 1)
            #pragma unroll
            for (int r = 0; r < 8; r++) if (r < s) s16[r] += s16[r + s];
        lrun += pairsum32(s16[0]);

        // T12 repack: P -> bf16 B-fragments via cvt_pk + permlane32_swap
        unsigned w0[8], w1[8];
        #pragma unroll
        for (int m = 0; m < 4; m++) {
            w0[m * 2]     = pk2(st0[4 * m], st0[4 * m + 1]);
            w0[m * 2 + 1] = pk2(st0[4 * m + 2], st0[4 * m + 3]);
            w1[m * 2]     = pk2(st1[4 * m], st1[4 * m + 1]);
            w1[m * 2 + 1] = pk2(st1[4 * m + 2], st1[4 * m + 3]);
        }
        short8 pf[4];
        #pragma unroll
        for (int ks = 0; ks < 4; ks++) {
            unsigned a0 = (ks < 2) ? w0[4 * (ks & 1) + 0] : w1[4 * (ks & 1) + 0];
            unsigned b0_ = (ks < 2) ? w0[4 * (ks & 1) + 2] : w1[4 * (ks & 1) + 2];
            unsigned a1 = (ks < 2) ? w0[4 * (ks & 1) + 1] : w1[4 * (ks & 1) + 1];
            unsigned b1_ = (ks < 2) ? w0[4 * (ks & 1) + 3] : w1[4 * (ks & 1) + 3];
            plswap(a0, b0_);
            plswap(a1, b1_);
            Frag f;
            f.u[0] = a0; f.u[1] = a1; f.u[2] = b0_; f.u[3] = b1_;
            pf[ks] = f.s8;
        }

        // transposed PV: O^T[d][q] += V^T * P^T
        __builtin_amdgcn_s_setprio(1);
        #pragma unroll
        for (int ks = 0; ks < 4; ks++) {
            short8 vf0 = *(const short8*)(vb + ((l31 * 128 + ks * 32 + hi * 16) ^ (l7 << 4)));
            short8 vf1 = *(const short8*)(vb + (((32 + l31) * 128 + ks * 32 + hi * 16) ^ (l7 << 4)));
            ot0 = __builtin_amdgcn_mfma_f32_32x32x16_bf16(vf0, pf[ks], ot0, 0, 0, 0);
            ot1 = __builtin_amdgcn_mfma_f32_32x32x16_bf16(vf1, pf[ks], ot1, 0, 0, 0);
        }
        __builtin_amdgcn_s_setprio(0);

        // publish next tile into the other buffer; single barrier per iteration.
        // Safety: buf[cur^1] was last READ in iter t-1, fully before the barrier
        // that ended iter t-1; these writes are after it. Next iter's reads of
        // buf[cur^1] are after this iter's barrier. One barrier suffices.
        if (t + 1 < NT) {
            char* kw = (char*)Ks[cur ^ 1];
            char* vw = (char*)Vs[cur ^ 1];
            #pragma unroll
            for (int i = 0; i < 2; i++) {
                int row = srow + 32 * i;
                *(short8*)(kw + ((row * 128 + ssl * 16) ^ ((row & 7) << 4))) = nk[i];
                *(short8*)(vw + ((row * 128 + ssl * 16) ^ ((row & 7) << 4))) = nv[i];
            }
        }
        __syncthreads();
    }

    // epilogue: normalize + store O[q][d] bf16 into AOb[b*SEQ+s][h*64+d]
    float inv = 1.f / lrun;
    int srow_q = b * SEQ + q0 + wid * 32 + l31;
    short* outp = AOb + (size_t)srow_q * DMODEL + h * DK;
    #pragma unroll
    for (int g = 0; g < 4; g++) {
        int d0 = 8 * g + 4 * hi;
        uint2 u;
        u.x = pk2(ot0[4 * g] * inv, ot0[4 * g + 1] * inv);
        u.y = pk2(ot0[4 * g + 2] * inv, ot0[4 * g + 3] * inv);
        *(uint2*)&outp[d0] = u;
        uint2 v2;
        v2.x = pk2(ot1[4 * g] * inv, ot1[4 * g + 1] * inv);
        v2.y = pk2(ot1[4 * g + 2] * inv, ot1[4 * g + 3] * inv);
        *(uint2*)&outp[32 + d0] = v2;
    }
}

extern "C" void kernel_launch(void* const* d_in, const int* in_sizes, int n_in,
                              void* d_out, int out_size, void* d_ws, size_t ws_size,
                              hipStream_t stream)
{
    const float* x  = (const float*)d_in[0];
    const float* Wq = (const float*)d_in[1];
    const float* bq = (const float*)d_in[2];
    const float* Wk = (const float*)d_in[3];
    const float* bk = (const float*)d_in[4];
    const float* Wv = (const float*)d_in[5];
    const float* bv = (const float*)d_in[6];
    const float* Wo = (const float*)d_in[7];
    const float* bo = (const float*)d_in[8];
    float* out = (float*)d_out;

    char* w = (char*)d_ws;
    short* xb    = (short*)w; w += (size_t)MTOT * DMODEL * 2;
    short* Wqkvt = (short*)w; w += (size_t)3 * DMODEL * DMODEL * 2;
    short* Wot   = (short*)w; w += (size_t)DMODEL * DMODEL * 2;
    short* Qb    = (short*)w; w += (size_t)MTOT * DMODEL * 2;
    short* Kb    = (short*)w; w += (size_t)MTOT * DMODEL * 2;
    short* Vtb   = (short*)w; w += (size_t)MTOT * DMODEL * 2;
    short* AOb   = (short*)w; w += (size_t)MTOT * DMODEL * 2;

    prep_kernel<<<NCVT + 4096, 256, 0, stream>>>(x, xb, Wq, Wk, Wv, Wo, Wqkvt, Wot);

    gemm_kernel<0><<<dim3(3 * DMODEL / 128, MTOT / 128), 256, 0, stream>>>(
        xb, Wqkvt, bq, bk, bv, Qb, Kb, Vtb, nullptr);

    attn_kernel<<<dim3(SEQ / 128 * NH * NB), 256, 0, stream>>>(Qb, Kb, Vtb, AOb);

    gemm_kernel<1><<<dim3(DMODEL / 128, MTOT / 128), 256, 0, stream>>>(
        AOb, Wot, bo, nullptr, nullptr, nullptr, nullptr, nullptr, out);
}

// Round 6
// 222.630 us; speedup vs baseline: 1.9716x; 1.0077x over previous
//
#include <hip/hip_runtime.h>

// MHA forward, bf16-MFMA pipeline.
// ws: xb(16M) | Wqkv_t(6M) | Wo_t(2M) | Q(16M) | K(16M) | Vt(16M) | AO(16M)

typedef short short8 __attribute__((ext_vector_type(8)));
typedef float f32x4 __attribute__((ext_vector_type(4)));
typedef float f32x16 __attribute__((ext_vector_type(16)));

#define DMODEL 1024
#define NH 16
#define DK 64
#define SEQ 2048
#define NB 4
#define MTOT (NB*SEQ)   // 8192
// 1/sqrt(dk) * log2(e)  — folded into K at projection time; softmax runs in exp2 domain
#define KSCALE 0.18033688f

__device__ __forceinline__ unsigned short f2bf(float f) {
    union { float f; unsigned u; } v; v.f = f;
    unsigned r = (v.u + 0x7FFFu + ((v.u >> 16) & 1u)) >> 16;  // RNE
    return (unsigned short)r;
}

__device__ __forceinline__ unsigned pk2(float a, float b) {
    unsigned r;
    asm("v_cvt_pk_bf16_f32 %0, %1, %2" : "=v"(r) : "v"(a), "v"(b));
    return r;
}

__device__ __forceinline__ float exp2a(float x) {
    float r; asm("v_exp_f32 %0, %1" : "=v"(r) : "v"(x)); return r;
}

__device__ __forceinline__ float max3a(float a, float b, float c) {
    float r; asm("v_max3_f32 %0, %1, %2, %3" : "=v"(r) : "v"(a), "v"(b), "v"(c)); return r;
}

// v_permlane32_swap_b32: vdst lanes 32-63 <-> vsrc lanes 0-31 (both modified)
__device__ __forceinline__ void plswap(unsigned &a, unsigned &b) {
    asm volatile("v_permlane32_swap_b32 %0, %1" : "+v"(a), "+v"(b));
}

// async global->LDS, 16B per lane; lds dest is wave-uniform base (+lane*16)
__device__ __forceinline__ void gload16(const short* g, short* l) {
    __builtin_amdgcn_global_load_lds(
        (const __attribute__((address_space(1))) unsigned*)(const void*)g,
        (__attribute__((address_space(3))) unsigned*)(void*)l,
        16, 0, 0);
}

__device__ __forceinline__ void vm8()   { asm volatile("s_waitcnt vmcnt(8)"   ::: "memory"); }
__device__ __forceinline__ void vm4()   { asm volatile("s_waitcnt vmcnt(4)"   ::: "memory"); }
__device__ __forceinline__ void vm0()   { asm volatile("s_waitcnt vmcnt(0)"   ::: "memory"); }
__device__ __forceinline__ void lgkm0() { asm volatile("s_waitcnt lgkmcnt(0)" ::: "memory"); }

union Frag { short8 s8; unsigned u[4]; };

// ---------- fused prep: x fp32->bf16 convert + 4x W transpose ----------
#define NCVT (MTOT * DMODEL / 4 / 256)   // 8192
__global__ __launch_bounds__(256) void prep_kernel(
    const float* __restrict__ x, short* __restrict__ xb,
    const float* __restrict__ Wq, const float* __restrict__ Wk,
    const float* __restrict__ Wv, const float* __restrict__ Wo,
    short* __restrict__ Wqkvt, short* __restrict__ Wot)
{
    __shared__ float t[32][33];
    int bid = blockIdx.x;
    if (bid < NCVT) {
        int i = bid * 256 + threadIdx.x;
        float4 v = ((const float4*)x)[i];
        short4 o;
        o.x = (short)f2bf(v.x); o.y = (short)f2bf(v.y);
        o.z = (short)f2bf(v.z); o.w = (short)f2bf(v.w);
        ((short4*)xb)[i] = o;
        return;
    }
    int wb = bid - NCVT;                 // 0..4095
    int widx = wb >> 10, tile = wb & 1023;
    const float* W = (widx == 0) ? Wq : (widx == 1) ? Wk : (widx == 2) ? Wv : Wo;
    short* dst = (widx < 3) ? (Wqkvt + (size_t)widx * DMODEL * DMODEL) : Wot;
    int r0 = (tile >> 5) * 32, c0 = (tile & 31) * 32;
    int tr = threadIdx.x >> 3;
    int tc = (threadIdx.x & 7) * 4;
    float4 v = *(const float4*)&W[(r0 + tr) * DMODEL + c0 + tc];
    t[tr][tc + 0] = v.x; t[tr][tc + 1] = v.y; t[tr][tc + 2] = v.z; t[tr][tc + 3] = v.w;
    __syncthreads();
    short4 o;
    o.x = (short)f2bf(t[tc + 0][tr]);
    o.y = (short)f2bf(t[tc + 1][tr]);
    o.z = (short)f2bf(t[tc + 2][tr]);
    o.w = (short)f2bf(t[tc + 3][tr]);
    *(short4*)&dst[(c0 + tr) * DMODEL + r0 + tc] = o;
}

// ---------- 128x128 bf16 GEMM, counted-vmcnt 2-phase pipeline ----------
// K-tile (BK=64) split into column-halves [128][32]; LDS [2buf][A/B][kkh],
// double-buffered by K-tile parity. Staging: 2 gloads/thread per half pair,
// issued 1.5 K-tiles ahead; vmcnt(8) guard before each phase-end barrier.
template<int MODE>
__global__ __launch_bounds__(256) void gemm_kernel(
    const short* __restrict__ A, const short* __restrict__ Bt,
    const float* __restrict__ b0, const float* __restrict__ b1, const float* __restrict__ b2,
    short* __restrict__ Qb, short* __restrict__ Kb, short* __restrict__ Vtb,
    float* __restrict__ Cout)
{
    __shared__ __align__(16) short L[2][2][2][128 * 32];   // [buf][A/B][kkh][r*32+c]
    const int K = DMODEL;
    const int NKT = K / 64;   // 16
    int m0 = blockIdx.y * 128, n0 = blockIdx.x * 128;
    int tid = threadIdx.x, lane = tid & 63, wid = tid >> 6;
    int wm = (wid >> 1) * 64, wn = (wid & 1) * 64;

    // staging source: lane covers row (lane>>2) of a 16-row band, 16B chunk (lane&3),
    // column pre-swizzled by ((row>>1)&3) = (lane>>3)&3  (inverse of read swizzle)
    int srowl = (lane >> 2);
    int scoll = ((lane & 3) ^ ((lane >> 3) & 3)) * 8;
    const short* aSrc = A + (size_t)(m0 + wid * 32 + srowl) * K + scoll;
    const short* bSrc = Bt + (size_t)(n0 + wid * 32 + srowl) * K + scoll;

    f32x4 acc[4][4];
    #pragma unroll
    for (int i = 0; i < 4; i++)
        #pragma unroll
        for (int j = 0; j < 4; j++) acc[i][j] = (f32x4){0.f, 0.f, 0.f, 0.f};

    // stage the (A,B) column-half kkh of K-tile kt into buffer kt&1
    auto STAGE = [&](int kt, int kkh) {
        int buf = kt & 1;
        const short* as = aSrc + (size_t)kt * 64 + kkh * 32;
        const short* bs = bSrc + (size_t)kt * 64 + kkh * 32;
        #pragma unroll
        for (int i = 0; i < 2; ++i) {
            gload16(as + (size_t)i * 16 * K, &L[buf][0][kkh][(wid * 32 + i * 16) * 32]);
            gload16(bs + (size_t)i * 16 * K, &L[buf][1][kkh][(wid * 32 + i * 16) * 32]);
        }
    };
    // fragment loads: logical chunk (lane>>4) at physical chunk ^((r>>1)&3)
    auto LDA = [&](int buf, int kkh, short8* f) {
        #pragma unroll
        for (int m = 0; m < 4; m++) {
            int r = wm + m * 16 + (lane & 15);
            f[m] = *(const short8*)&L[buf][0][kkh][r * 32 + (((lane >> 4) ^ ((r >> 1) & 3)) * 8)];
        }
    };
    auto LDB = [&](int buf, int kkh, short8* f) {
        #pragma unroll
        for (int n = 0; n < 4; n++) {
            int r = wn + n * 16 + (lane & 15);
            f[n] = *(const short8*)&L[buf][1][kkh][r * 32 + (((lane >> 4) ^ ((r >> 1) & 3)) * 8)];
        }
    };

    // prologue: A0B0(0), A1B1(0), A0B0(1); certify oldest group, rendezvous
    STAGE(0, 0);
    STAGE(0, 1);
    STAGE(1, 0);
    vm8();
    __builtin_amdgcn_s_barrier();

    for (int k = 0; k < NKT; ++k) {
        int buf = k & 1;
        // ---- phase A (kk = 0): reads A0B0(k), stages A1B1(k+1)
        {
            short8 af[4], bfv[4];
            LDA(buf, 0, af); LDB(buf, 0, bfv);
            if (k + 1 < NKT) STAGE(k + 1, 1);
            lgkm0();
            __builtin_amdgcn_s_barrier();
            __builtin_amdgcn_s_setprio(1);
            #pragma unroll
            for (int i = 0; i < 4; i++)
                #pragma unroll
                for (int j = 0; j < 4; j++)
                    acc[i][j] = __builtin_amdgcn_mfma_f32_16x16x32_bf16(af[i], bfv[j], acc[i][j], 0, 0, 0);
            __builtin_amdgcn_s_setprio(0);
            // guard next phase's reads (A1B1(k)): allow 2 newer half-pairs
            if (k == NKT - 1) vm0(); else vm8();
            __builtin_amdgcn_s_barrier();
        }
        // ---- phase B (kk = 1): reads A1B1(k), stages A0B0(k+2)
        {
            short8 af[4], bfv[4];
            LDA(buf, 1, af); LDB(buf, 1, bfv);
            if (k + 2 < NKT) STAGE(k + 2, 0);
            lgkm0();
            __builtin_amdgcn_s_barrier();
            __builtin_amdgcn_s_setprio(1);
            #pragma unroll
            for (int i = 0; i < 4; i++)
                #pragma unroll
                for (int j = 0; j < 4; j++)
                    acc[i][j] = __builtin_amdgcn_mfma_f32_16x16x32_bf16(af[i], bfv[j], acc[i][j], 0, 0, 0);
            __builtin_amdgcn_s_setprio(0);
            if (k < NKT - 1) {
                if (k == NKT - 2) vm4(); else vm8();
                __builtin_amdgcn_s_barrier();
            }
        }
    }

    #pragma unroll
    for (int i = 0; i < 4; i++) {
        #pragma unroll
        for (int j = 0; j < 4; j++) {
            int col = n0 + wn + j * 16 + (lane & 15);
            #pragma unroll
            for (int r = 0; r < 4; r++) {
                int row = m0 + wm + i * 16 + (lane >> 4) * 4 + r;
                float v = acc[i][j][r];
                if (MODE == 0) {
                    int seg = col >> 10, c = col & 1023;
                    const float* bp = (seg == 0) ? b0 : (seg == 1 ? b1 : b2);
                    v += bp[c];
                    if (seg == 1) v *= KSCALE;   // fold softmax scale*log2e into K
                    unsigned short bv = f2bf(v);
                    int hh = c >> 6, d = c & 63, bb = row >> 11, s = row & 2047;
                    if (seg == 0)      Qb [(((bb * NH + hh) * SEQ) + s) * DK + d] = (short)bv;
                    else if (seg == 1) Kb [(((bb * NH + hh) * SEQ) + s) * DK + d] = (short)bv;
                    else               Vtb[(((bb * NH + hh) * DK) + d) * SEQ + s] = (short)bv;
                } else {
                    Cout[row * DMODEL + col] = v + b0[col];
                }
            }
        }
    }
}

// ---------- flash attention (round-4 proven version, 107 us) ----------
// swapped-QK^T 32x32, exp2-domain softmax, 4 waves, 32 q/wave, KV tiles 64.
// Single-buffer LDS; T14 reg prefetch; write after barrier; 2 barriers/tile.
__global__ __launch_bounds__(256) void attn_kernel(
    const short* __restrict__ Qb, const short* __restrict__ Kb,
    const short* __restrict__ Vtb, short* __restrict__ AOb)
{
    __shared__ __align__(16) short Ks[64 * 64];
    __shared__ __align__(16) short Vs[64 * 64];
    char* ksb = (char*)Ks;
    char* vsb = (char*)Vs;

    int bid = blockIdx.x;                       // 0..1023
    int wk = (bid & 7) * 128 + (bid >> 3);      // XCD-contiguous work
    int qi = wk & 15, bh = wk >> 4;
    int h = bh & (NH - 1), b = bh >> 4;
    int q0 = qi * 128;

    int tid = threadIdx.x, lane = tid & 63, wid = tid >> 6;
    int hi = lane >> 5, l31 = lane & 31, l7 = lane & 7;
    const short* Qp = Qb + (size_t)bh * SEQ * DK;
    const short* Kp = Kb + (size_t)bh * SEQ * DK;
    const short* Vp = Vtb + (size_t)bh * DK * SEQ;

    // Q fragments (B-operand): lane holds Q[q=l31][ks*16+hi*8+j]
    short8 qf[4];
    #pragma unroll
    for (int ks = 0; ks < 4; ks++)
        qf[ks] = *(const short8*)&Qp[(q0 + wid * 32 + l31) * DK + ks * 16 + hi * 8];

    f32x16 ot0, ot1;
    #pragma unroll
    for (int r = 0; r < 16; r++) { ot0[r] = 0.f; ot1[r] = 0.f; }
    float mrun = -1e30f, lrun = 0.f;

    int srow = tid >> 3, ssl = tid & 7;   // staging: 256 threads x 2 chunks
    #pragma unroll
    for (int i = 0; i < 2; i++) {
        int row = srow + 32 * i;
        *(short8*)(ksb + ((row * 128 + ssl * 16) ^ ((row & 7) << 4))) =
            *(const short8*)&Kp[row * DK + ssl * 8];
        *(short8*)(vsb + ((row * 128 + ssl * 16) ^ ((row & 7) << 4))) =
            *(const short8*)&Vp[row * SEQ + ssl * 8];
    }
    __syncthreads();

    const int NT = SEQ / 64;
    for (int t = 0; t < NT; ++t) {
        // T14: prefetch next tile into regs (latency hides under compute)
        short8 nk[2], nv[2];
        if (t + 1 < NT) {
            int kv0n = (t + 1) * 64;
            #pragma unroll
            for (int i = 0; i < 2; i++) {
                int row = srow + 32 * i;
                nk[i] = *(const short8*)&Kp[(kv0n + row) * DK + ssl * 8];
                nv[i] = *(const short8*)&Vp[row * SEQ + kv0n + ssl * 8];
            }
        }

        // swapped QK^T: St[kv][q]
        f32x16 st0, st1;
        #pragma unroll
        for (int r = 0; r < 16; r++) { st0[r] = 0.f; st1[r] = 0.f; }
        __builtin_amdgcn_s_setprio(1);
        #pragma unroll
        for (int ks = 0; ks < 4; ks++) {
            short8 kf0 = *(const short8*)(ksb + ((l31 * 128 + ks * 32 + hi * 16) ^ (l7 << 4)));
            short8 kf1 = *(const short8*)(ksb + (((32 + l31) * 128 + ks * 32 + hi * 16) ^ (l7 << 4)));
            st0 = __builtin_amdgcn_mfma_f32_32x32x16_bf16(kf0, qf[ks], st0, 0, 0, 0);
            st1 = __builtin_amdgcn_mfma_f32_32x32x16_bf16(kf1, qf[ks], st1, 0, 0, 0);
        }
        __builtin_amdgcn_s_setprio(0);

        // row max via max3 tree (32 values -> 1), then lane-pair exchange
        float m8[8];
        #pragma unroll
        for (int i = 0; i < 8; i++) m8[i] = max3a(st0[i], st0[i + 8], st1[i]);
        float m4[4];
        #pragma unroll
        for (int i = 0; i < 4; i++) m4[i] = max3a(m8[i], m8[i + 4], st1[i + 8]);
        float m2a = max3a(m4[0], m4[2], st1[12]);
        float m2b = max3a(m4[1], m4[3], st1[13]);
        float mxv = max3a(m2a, m2b, st1[14]);
        mxv = fmaxf(mxv, st1[15]);
        float mt = fmaxf(mxv, __shfl_xor(mxv, 32, 64));

        // T13 defer-max (log2 domain, threshold 11 -> P bounded by 2^11)
        if (!__all(mt - mrun <= 11.0f)) {
            float mn = fmaxf(mrun, mt);
            float al = exp2a(mrun - mn);
            lrun *= al;
            #pragma unroll
            for (int r = 0; r < 16; r++) { ot0[r] *= al; ot1[r] *= al; }
            mrun = mn;
        }
        #pragma unroll
        for (int r = 0; r < 16; r++) {
            st0[r] = exp2a(st0[r] - mrun);
            st1[r] = exp2a(st1[r] - mrun);
        }
        float s16[16];
        #pragma unroll
        for (int r = 0; r < 16; r++) s16[r] = st0[r] + st1[r];
        #pragma unroll
        for (int s = 8; s > 0; s >>= 1)
            #pragma unroll
            for (int r = 0; r < 8; r++) if (r < s) s16[r] += s16[r + s];
        lrun += s16[0] + __shfl_xor(s16[0], 32, 64);

        // T12 repack: P -> bf16 B-fragments via cvt_pk + permlane32_swap
        unsigned w0[8], w1[8];
        #pragma unroll
        for (int m = 0; m < 4; m++) {
            w0[m * 2]     = pk2(st0[4 * m], st0[4 * m + 1]);
            w0[m * 2 + 1] = pk2(st0[4 * m + 2], st0[4 * m + 3]);
            w1[m * 2]     = pk2(st1[4 * m], st1[4 * m + 1]);
            w1[m * 2 + 1] = pk2(st1[4 * m + 2], st1[4 * m + 3]);
        }
        short8 pf[4];
        #pragma unroll
        for (int ks = 0; ks < 4; ks++) {
            unsigned a0 = (ks < 2) ? w0[4 * (ks & 1) + 0] : w1[4 * (ks & 1) + 0];
            unsigned b0_ = (ks < 2) ? w0[4 * (ks & 1) + 2] : w1[4 * (ks & 1) + 2];
            unsigned a1 = (ks < 2) ? w0[4 * (ks & 1) + 1] : w1[4 * (ks & 1) + 1];
            unsigned b1_ = (ks < 2) ? w0[4 * (ks & 1) + 3] : w1[4 * (ks & 1) + 3];
            plswap(a0, b0_);
            plswap(a1, b1_);
            Frag f;
            f.u[0] = a0; f.u[1] = a1; f.u[2] = b0_; f.u[3] = b1_;
            pf[ks] = f.s8;
        }

        // transposed PV: O^T[d][q] += V^T * P^T
        __builtin_amdgcn_s_setprio(1);
        #pragma unroll
        for (int ks = 0; ks < 4; ks++) {
            short8 vf0 = *(const short8*)(vsb + ((l31 * 128 + ks * 32 + hi * 16) ^ (l7 << 4)));
            short8 vf1 = *(const short8*)(vsb + (((32 + l31) * 128 + ks * 32 + hi * 16) ^ (l7 << 4)));
            ot0 = __builtin_amdgcn_mfma_f32_32x32x16_bf16(vf0, pf[ks], ot0, 0, 0, 0);
            ot1 = __builtin_amdgcn_mfma_f32_32x32x16_bf16(vf1, pf[ks], ot1, 0, 0, 0);
        }
        __builtin_amdgcn_s_setprio(0);

        __syncthreads();
        if (t + 1 < NT) {
            #pragma unroll
            for (int i = 0; i < 2; i++) {
                int row = srow + 32 * i;
                *(short8*)(ksb + ((row * 128 + ssl * 16) ^ ((row & 7) << 4))) = nk[i];
                *(short8*)(vsb + ((row * 128 + ssl * 16) ^ ((row & 7) << 4))) = nv[i];
            }
        }
        __syncthreads();
    }

    // epilogue: normalize + store O[q][d] bf16 into AOb[b*SEQ+s][h*64+d]
    float inv = 1.f / lrun;
    int srow_q = b * SEQ + q0 + wid * 32 + l31;
    short* outp = AOb + (size_t)srow_q * DMODEL + h * DK;
    #pragma unroll
    for (int g = 0; g < 4; g++) {
        int d0 = 8 * g + 4 * hi;
        uint2 u;
        u.x = pk2(ot0[4 * g] * inv, ot0[4 * g + 1] * inv);
        u.y = pk2(ot0[4 * g + 2] * inv, ot0[4 * g + 3] * inv);
        *(uint2*)&outp[d0] = u;
        uint2 v2;
        v2.x = pk2(ot1[4 * g] * inv, ot1[4 * g + 1] * inv);
        v2.y = pk2(ot1[4 * g + 2] * inv, ot1[4 * g + 3] * inv);
        *(uint2*)&outp[32 + d0] = v2;
    }
}

extern "C" void kernel_launch(void* const* d_in, const int* in_sizes, int n_in,
                              void* d_out, int out_size, void* d_ws, size_t ws_size,
                              hipStream_t stream)
{
    const float* x  = (const float*)d_in[0];
    const float* Wq = (const float*)d_in[1];
    const float* bq = (const float*)d_in[2];
    const float* Wk = (const float*)d_in[3];
    const float* bk = (const float*)d_in[4];
    const float* Wv = (const float*)d_in[5];
    const float* bv = (const float*)d_in[6];
    const float* Wo = (const float*)d_in[7];
    const float* bo = (const float*)d_in[8];
    float* out = (float*)d_out;

    char* w = (char*)d_ws;
    short* xb    = (short*)w; w += (size_t)MTOT * DMODEL * 2;
    short* Wqkvt = (short*)w; w += (size_t)3 * DMODEL * DMODEL * 2;
    short* Wot   = (short*)w; w += (size_t)DMODEL * DMODEL * 2;
    short* Qb    = (short*)w; w += (size_t)MTOT * DMODEL * 2;
    short* Kb    = (short*)w; w += (size_t)MTOT * DMODEL * 2;
    short* Vtb   = (short*)w; w += (size_t)MTOT * DMODEL * 2;
    short* AOb   = (short*)w; w += (size_t)MTOT * DMODEL * 2;

    prep_kernel<<<NCVT + 4096, 256, 0, stream>>>(x, xb, Wq, Wk, Wv, Wo, Wqkvt, Wot);

    gemm_kernel<0><<<dim3(3 * DMODEL / 128, MTOT / 128), 256, 0, stream>>>(
        xb, Wqkvt, bq, bk, bv, Qb, Kb, Vtb, nullptr);

    attn_kernel<<<dim3(SEQ / 128 * NH * NB), 256, 0, stream>>>(Qb, Kb, Vtb, AOb);

    gemm_kernel<1><<<dim3(DMODEL / 128, MTOT / 128), 256, 0, stream>>>(
        AOb, Wot, bo, nullptr, nullptr, nullptr, nullptr, nullptr, out);
}